// Round 9
// baseline (127.010 us; speedup 1.0000x reference)
//
#include <hip/hip_runtime.h>
#include <math.h>

#define NB 32
#define NT 512
#define NS 64
#define NOBS 4
#define NEMB 32
#define NPE 16
#define NATTN 10
#define ND 26  // ATTN + PE

// obs_emb_weights LDS layout: 64 rows (sensor s) x 128 dwords (o*32+e),
// 16B-chunk XOR swizzle so per-lane ds_read_b128 of row s spreads banks.
__device__ __forceinline__ int obs_idx(int s, int chunk) {
    return (s << 7) + (((chunk ^ (s & 7)) & 31) << 2);
}

__global__ __launch_bounds__(512)
void raindrop_kernel(const float* __restrict__ x,
                     const float* __restrict__ times,
                     const float* __restrict__ mask,
                     const float* __restrict__ obsW,
                     const float* __restrict__ attnW,
                     const float* __restrict__ recvW,
                     const float* __restrict__ recvB,
                     float* __restrict__ out)
{
    // Separate regions; obsW tile is NEVER overwritten -> staged once,
    // exactly ONE barrier in the whole kernel. 57 KiB -> 2 blocks/CU.
    __shared__ float obsw_lds[NS * 128];   // 32 KiB
    __shared__ float hq_lds[8 * NS * 12];  // 24 KiB (per-wave 3 KiB rows)
    __shared__ float wpe[8 * NEMB];        // 1 KiB  (per-wave strip)

    const int tid = threadIdx.x;

    // Stage S*OBS*EMB = 8192 floats into LDS (coalesced global float4 reads,
    // swizzled LDS writes). 512 threads x 4 iters x 4 floats.
#pragma unroll
    for (int k = 0; k < 4; ++k) {
        int i = (tid << 2) + (k << 11);
        float4 v = *reinterpret_cast<const float4*>(obsW + i);
        *reinterpret_cast<float4*>(&obsw_lds[obs_idx(i >> 7, (i & 127) >> 2)]) = v;
    }

    const int lane = tid & 63;
    const int wv = tid >> 6;
    const int s = lane;          // phase-1 role: lane = sensor
    const int g = lane >> 4;     // phase-3 row group
    const int iu = lane & 15;    // phase-3 u-quad owner

    // per-lane attnW quad for phase 3 (40 VGPRs, loaded once per kernel)
    float aw0[NATTN], aw1[NATTN], aw2[NATTN], aw3[NATTN];
    {
        const float2* ap = reinterpret_cast<const float2*>(attnW + (iu * 4) * NATTN);
#pragma unroll
        for (int q = 0; q < 5; ++q) {
            float2 v0 = ap[q];      aw0[2*q] = v0.x; aw0[2*q+1] = v0.y;
            float2 v1 = ap[5 + q];  aw1[2*q] = v1.x; aw1[2*q+1] = v1.y;
            float2 v2 = ap[10 + q]; aw2[2*q] = v2.x; aw2[2*q+1] = v2.y;
            float2 v3 = ap[15 + q]; aw3[2*q] = v3.x; aw3[2*q+1] = v3.y;
        }
    }

    __syncthreads();  // obsW tile ready — the ONLY barrier in the kernel

    float* hbase = &hq_lds[wv * (NS * 12)];
    const float* hgbase = hbase + g * 12;
    float* wpw = &wpe[wv * NEMB];

    const float divs[8] = {1.0f, 0.31622776601683794f, 0.1f, 0.031622776601683794f,
                           0.01f, 0.0031622776601683794f, 0.001f, 0.00031622776601683794f};

    // 4 bt-tiles per wave, NO barriers between tiles: wpe/hq staging is
    // same-wave write->read (DS ops from one wave complete in program order,
    // proven across R5-R8). Waves desync -> stores stream continuously.
#pragma unroll 1
    for (int t = 0; t < 4; ++t) {
        const int bt = (blockIdx.x << 5) + (t << 3) + wv;

        // positional encoding (wave-uniform); native sin/cos
        const float tt = times[bt];
        float pe[NPE];
#pragma unroll
        for (int i = 0; i < 8; ++i) {
            float ang = tt * divs[i];
            pe[2 * i]     = __sinf(ang);
            pe[2 * i + 1] = __cosf(ang);
        }

        // c0 = recvB[10:26] . pe  (uniform; recvB via s_load)
        float c0 = 0.f;
#pragma unroll
        for (int p = 0; p < NPE; ++p) c0 += recvB[NATTN + p] * pe[p];

        // w_pe: lane e (= lane&31) folds recvW[e][10..25] with pe -> LDS strip
        {
            const int e = lane & 31;
            const float2* rp = reinterpret_cast<const float2*>(recvW + e * ND + NATTN);
            float acc = 0.f;
#pragma unroll
            for (int p2 = 0; p2 < 8; ++p2) {
                float2 w = rp[p2];
                acc += w.x * pe[2 * p2];
                acc += w.y * pe[2 * p2 + 1];
            }
            if (lane < NEMB) wpw[e] = acc;
        }

        // per-lane inputs (coalesced: 64 lanes x 16B contiguous)
        const float4 xv = *reinterpret_cast<const float4*>(x + ((size_t)bt * NS + s) * NOBS);
        const float  mv = mask[(size_t)bt * NS + s];

        // hq[a] = recv_b[a] + sum_e h_e * recv_W[e][a]   (a = 0..9 only)
        // beta' = sum_e h_e * w_pe[e]
        float hq[NATTN];
#pragma unroll
        for (int a = 0; a < NATTN; ++a) hq[a] = recvB[a];  // uniform -> s_load
        float betah = 0.f;

#pragma unroll
        for (int eb = 0; eb < 8; ++eb) {  // e = eb*4 + j
            float a0 = 0.f, a1 = 0.f, a2 = 0.f, a3 = 0.f;
            {
                float4 w0 = *reinterpret_cast<const float4*>(&obsw_lds[obs_idx(s, 0 * 8 + eb)]);
                a0 += xv.x * w0.x; a1 += xv.x * w0.y; a2 += xv.x * w0.z; a3 += xv.x * w0.w;
                float4 w1 = *reinterpret_cast<const float4*>(&obsw_lds[obs_idx(s, 1 * 8 + eb)]);
                a0 += xv.y * w1.x; a1 += xv.y * w1.y; a2 += xv.y * w1.z; a3 += xv.y * w1.w;
                float4 w2 = *reinterpret_cast<const float4*>(&obsw_lds[obs_idx(s, 2 * 8 + eb)]);
                a0 += xv.z * w2.x; a1 += xv.z * w2.y; a2 += xv.z * w2.z; a3 += xv.z * w2.w;
                float4 w3 = *reinterpret_cast<const float4*>(&obsw_lds[obs_idx(s, 3 * 8 + eb)]);
                a0 += xv.w * w3.x; a1 += xv.w * w3.y; a2 += xv.w * w3.z; a3 += xv.w * w3.w;
            }
            const float h0 = fmaxf(a0, 0.f) * mv;
            const float h1 = fmaxf(a1, 0.f) * mv;
            const float h2 = fmaxf(a2, 0.f) * mv;
            const float h3 = fmaxf(a3, 0.f) * mv;

            // beta' contribution: uniform ds_read_b128 broadcast of 4 w_pe
            float4 wp = *reinterpret_cast<const float4*>(wpw + eb * 4);
            betah += h0 * wp.x + h1 * wp.y + h2 * wp.z + h3 * wp.w;

            const float* rw = recvW + (eb * 4) * ND;  // uniform base -> s_load
#pragma unroll
            for (int a = 0; a < NATTN; ++a) {
                hq[a] += h0 * rw[a] + h1 * rw[ND + a] + h2 * rw[2 * ND + a] + h3 * rw[3 * ND + a];
            }
        }

        const float beta = c0 + betah;

        // Stage this wave's hq rows (private region; same-wave in-order DS)
        {
            float* hrow = hbase + s * 12;
            float4 v0 = {hq[0], hq[1], hq[2], hq[3]};
            float4 v1 = {hq[4], hq[5], hq[6], hq[7]};
            float4 v2 = {hq[8], hq[9], beta, 0.f};
            *reinterpret_cast<float4*>(hrow)     = v0;
            *reinterpret_cast<float4*>(hrow + 4) = v1;
            *reinterpret_cast<float4*>(hrow + 8) = v2;
        }

        // Phase 3: wave = 4 row-groups x 16 lanes. Group g reads row r+g
        // (rows 48B apart -> disjoint bank quads {0-3,12-15,24-27,4-7}),
        // 40 FMA/lane, one coalesced 1KB wave store (4 rows x 256B).
        float* optr = out + (size_t)bt * (NS * NS) + g * NS + iu * 4;
#pragma unroll 4
        for (int r = 0; r < NS; r += 4) {
            const float* hr = hgbase + r * 12;
            float4 h0 = *reinterpret_cast<const float4*>(hr);
            float4 h1 = *reinterpret_cast<const float4*>(hr + 4);
            float4 h2 = *reinterpret_cast<const float4*>(hr + 8);
            float acc0 = h2.z, acc1 = h2.z, acc2 = h2.z, acc3 = h2.z;  // beta_r
            acc0 += h0.x * aw0[0]; acc1 += h0.x * aw1[0]; acc2 += h0.x * aw2[0]; acc3 += h0.x * aw3[0];
            acc0 += h0.y * aw0[1]; acc1 += h0.y * aw1[1]; acc2 += h0.y * aw2[1]; acc3 += h0.y * aw3[1];
            acc0 += h0.z * aw0[2]; acc1 += h0.z * aw1[2]; acc2 += h0.z * aw2[2]; acc3 += h0.z * aw3[2];
            acc0 += h0.w * aw0[3]; acc1 += h0.w * aw1[3]; acc2 += h0.w * aw2[3]; acc3 += h0.w * aw3[3];
            acc0 += h1.x * aw0[4]; acc1 += h1.x * aw1[4]; acc2 += h1.x * aw2[4]; acc3 += h1.x * aw3[4];
            acc0 += h1.y * aw0[5]; acc1 += h1.y * aw1[5]; acc2 += h1.y * aw2[5]; acc3 += h1.y * aw3[5];
            acc0 += h1.z * aw0[6]; acc1 += h1.z * aw1[6]; acc2 += h1.z * aw2[6]; acc3 += h1.z * aw3[6];
            acc0 += h1.w * aw0[7]; acc1 += h1.w * aw1[7]; acc2 += h1.w * aw2[7]; acc3 += h1.w * aw3[7];
            acc0 += h2.x * aw0[8]; acc1 += h2.x * aw1[8]; acc2 += h2.x * aw2[8]; acc3 += h2.x * aw3[8];
            acc0 += h2.y * aw0[9]; acc1 += h2.y * aw1[9]; acc2 += h2.y * aw2[9]; acc3 += h2.y * aw3[9];
            float4 rv;
            rv.x = fmaxf(acc0, 0.f);
            rv.y = fmaxf(acc1, 0.f);
            rv.z = fmaxf(acc2, 0.f);
            rv.w = fmaxf(acc3, 0.f);
            *reinterpret_cast<float4*>(optr) = rv;
            optr += 4 * NS;
        }
    }
}

extern "C" void kernel_launch(void* const* d_in, const int* in_sizes, int n_in,
                              void* d_out, int out_size, void* d_ws, size_t ws_size,
                              hipStream_t stream) {
    const float* x     = (const float*)d_in[0];
    const float* times = (const float*)d_in[1];
    const float* mask  = (const float*)d_in[2];
    const float* obsW  = (const float*)d_in[3];
    const float* attnW = (const float*)d_in[4];
    const float* recvW = (const float*)d_in[5];
    const float* recvB = (const float*)d_in[6];
    float* out = (float*)d_out;

    // 512 persistent-ish blocks (2/CU, LDS-bound), 32 bt-tiles per block:
    // wave wv of block b handles bt = b*32 + t*8 + wv, t = 0..3.
    raindrop_kernel<<<dim3(512), dim3(512), 0, stream>>>(
        x, times, mask, obsW, attnW, recvW, recvB, out);
}

// Round 10
// 93.186 us; speedup vs baseline: 1.3630x; 1.3630x over previous
//
#include <hip/hip_runtime.h>
#include <math.h>

#define NB 32
#define NT 512
#define NS 64
#define NOBS 4
#define NEMB 32
#define NPE 16
#define NATTN 10
#define ND 26  // ATTN + PE

// Pre-kernel: repack obsW [s][128] (dword d = o*32+e) into W3 [o][eb][s][j]
// (e = eb*4+j), so phase-1's per-(o,eb) fetch of 4 consecutive e for lane=s
// is one fully-coalesced global_load_dwordx4 (lane stride 16B).
__global__ __launch_bounds__(256)
void repack_obsw(const float* __restrict__ obsW, float* __restrict__ w3) {
    int i = blockIdx.x * 256 + threadIdx.x;   // 8192 output dwords
    int j = i & 3;
    int s = (i >> 2) & 63;
    int eb = (i >> 8) & 7;
    int o = i >> 11;
    w3[i] = obsW[s * 128 + o * 32 + eb * 4 + j];
}

__global__ __launch_bounds__(512)
void raindrop_kernel(const float* __restrict__ x,
                     const float* __restrict__ times,
                     const float* __restrict__ mask,
                     const float* __restrict__ w3,      // repacked obsW
                     const float* __restrict__ attnW,
                     const float* __restrict__ recvW,
                     const float* __restrict__ recvB,
                     float* __restrict__ out)
{
    // Only hq rows + wpe live in LDS now: 25 KiB -> 4 blocks/CU, 32 waves/CU.
    // ZERO barriers in this kernel: all LDS use is same-wave write->read.
    __shared__ float hq_lds[8 * NS * 12];  // 24 KiB (3 KiB per wave)
    __shared__ float wpe[8 * NEMB];        // 1 KiB  (per-wave strip)

    const int tid = threadIdx.x;
    const int lane = tid & 63;
    const int wv = tid >> 6;
    const int bt = blockIdx.x * 8 + wv;   // one wave per (b,t)
    const int s = lane;                   // phase-1 role: lane = sensor
    const int g = lane >> 4;              // phase-3 row group
    const int iu = lane & 15;             // phase-3 u-quad owner

    // per-lane attnW quad for phase 3 (40 VGPRs, loaded once)
    float aw0[NATTN], aw1[NATTN], aw2[NATTN], aw3[NATTN];
    {
        const float2* ap = reinterpret_cast<const float2*>(attnW + (iu * 4) * NATTN);
#pragma unroll
        for (int q = 0; q < 5; ++q) {
            float2 v0 = ap[q];      aw0[2*q] = v0.x; aw0[2*q+1] = v0.y;
            float2 v1 = ap[5 + q];  aw1[2*q] = v1.x; aw1[2*q+1] = v1.y;
            float2 v2 = ap[10 + q]; aw2[2*q] = v2.x; aw2[2*q+1] = v2.y;
            float2 v3 = ap[15 + q]; aw3[2*q] = v3.x; aw3[2*q+1] = v3.y;
        }
    }

    // positional encoding (wave-uniform; div[i] = 10^(-i/2)); native sin/cos
    const float tt = times[bt];
    const float divs[8] = {1.0f, 0.31622776601683794f, 0.1f, 0.031622776601683794f,
                           0.01f, 0.0031622776601683794f, 0.001f, 0.00031622776601683794f};
    float pe[NPE];
#pragma unroll
    for (int i = 0; i < 8; ++i) {
        float ang = tt * divs[i];
        pe[2 * i]     = __sinf(ang);
        pe[2 * i + 1] = __cosf(ang);
    }

    // c0 = recvB[10:26] . pe  (uniform; recvB via s_load)
    float c0 = 0.f;
#pragma unroll
    for (int p = 0; p < NPE; ++p) c0 += recvB[NATTN + p] * pe[p];

    // w_pe: lane e (= lane&31) folds recvW[e][10..25] with pe -> LDS strip.
    // Same-wave write->read; no barrier needed.
    float* wpw = &wpe[wv * NEMB];
    {
        const int e = lane & 31;
        const float2* rp = reinterpret_cast<const float2*>(recvW + e * ND + NATTN);
        float acc = 0.f;
#pragma unroll
        for (int p2 = 0; p2 < 8; ++p2) {
            float2 w = rp[p2];
            acc += w.x * pe[2 * p2];
            acc += w.y * pe[2 * p2 + 1];
        }
        if (lane < NEMB) wpw[e] = acc;
    }

    // per-lane inputs (coalesced: 64 lanes x 16B contiguous)
    const float4 xv = *reinterpret_cast<const float4*>(x + ((size_t)bt * NS + s) * NOBS);
    const float  mv = mask[(size_t)bt * NS + s];

    // hq[a] = recv_b[a] + sum_e h_e * recv_W[e][a]   (a = 0..9 only)
    // beta' = sum_e h_e * w_pe[e]
    float hq[NATTN];
#pragma unroll
    for (int a = 0; a < NATTN; ++a) hq[a] = recvB[a];  // uniform -> s_load
    float betah = 0.f;

    const float* wbase = w3 + (s << 2);  // lane's 16B slot in W3[o][eb][.][.]

#pragma unroll
    for (int eb = 0; eb < 8; ++eb) {  // e = eb*4 + j
        float a0 = 0.f, a1 = 0.f, a2 = 0.f, a3 = 0.f;
        {
            // W3[o][eb][s][0..3]: coalesced dwordx4, L1-resident (32KB total)
            float4 w0 = *reinterpret_cast<const float4*>(wbase + eb * 256);
            a0 += xv.x * w0.x; a1 += xv.x * w0.y; a2 += xv.x * w0.z; a3 += xv.x * w0.w;
            float4 w1 = *reinterpret_cast<const float4*>(wbase + 2048 + eb * 256);
            a0 += xv.y * w1.x; a1 += xv.y * w1.y; a2 += xv.y * w1.z; a3 += xv.y * w1.w;
            float4 w2 = *reinterpret_cast<const float4*>(wbase + 4096 + eb * 256);
            a0 += xv.z * w2.x; a1 += xv.z * w2.y; a2 += xv.z * w2.z; a3 += xv.z * w2.w;
            float4 w3v = *reinterpret_cast<const float4*>(wbase + 6144 + eb * 256);
            a0 += xv.w * w3v.x; a1 += xv.w * w3v.y; a2 += xv.w * w3v.z; a3 += xv.w * w3v.w;
        }
        const float h0 = fmaxf(a0, 0.f) * mv;
        const float h1 = fmaxf(a1, 0.f) * mv;
        const float h2 = fmaxf(a2, 0.f) * mv;
        const float h3 = fmaxf(a3, 0.f) * mv;

        // beta' contribution: uniform ds_read_b128 broadcast of 4 w_pe
        float4 wp = *reinterpret_cast<const float4*>(wpw + eb * 4);
        betah += h0 * wp.x + h1 * wp.y + h2 * wp.z + h3 * wp.w;

        const float* rw = recvW + (eb * 4) * ND;  // uniform base -> s_load
#pragma unroll
        for (int a = 0; a < NATTN; ++a) {
            hq[a] += h0 * rw[a] + h1 * rw[ND + a] + h2 * rw[2 * ND + a] + h3 * rw[3 * ND + a];
        }
    }

    const float beta = c0 + betah;

    // Stage this wave's hq rows (private region; same-wave in-order DS,
    // proven R5-R8; no barrier).
    float* hbase = &hq_lds[wv * (NS * 12)];
    {
        float* hrow = hbase + s * 12;
        float4 v0 = {hq[0], hq[1], hq[2], hq[3]};
        float4 v1 = {hq[4], hq[5], hq[6], hq[7]};
        float4 v2 = {hq[8], hq[9], beta, 0.f};
        *reinterpret_cast<float4*>(hrow)     = v0;
        *reinterpret_cast<float4*>(hrow + 4) = v1;
        *reinterpret_cast<float4*>(hrow + 8) = v2;
    }

    // Phase 3: wave = 4 row-groups x 16 lanes. Group g reads row r+g
    // (rows 48B apart -> disjoint bank quads, broadcast within group,
    // conflict-free), 40 FMA/lane, one coalesced 1KB wave store.
    const float* hgbase = hbase + g * 12;
    float* optr = out + (size_t)bt * (NS * NS) + g * NS + iu * 4;
#pragma unroll 4
    for (int r = 0; r < NS; r += 4) {
        const float* hr = hgbase + r * 12;
        float4 h0 = *reinterpret_cast<const float4*>(hr);
        float4 h1 = *reinterpret_cast<const float4*>(hr + 4);
        float4 h2 = *reinterpret_cast<const float4*>(hr + 8);
        float acc0 = h2.z, acc1 = h2.z, acc2 = h2.z, acc3 = h2.z;  // beta_r
        acc0 += h0.x * aw0[0]; acc1 += h0.x * aw1[0]; acc2 += h0.x * aw2[0]; acc3 += h0.x * aw3[0];
        acc0 += h0.y * aw0[1]; acc1 += h0.y * aw1[1]; acc2 += h0.y * aw2[1]; acc3 += h0.y * aw3[1];
        acc0 += h0.z * aw0[2]; acc1 += h0.z * aw1[2]; acc2 += h0.z * aw2[2]; acc3 += h0.z * aw3[2];
        acc0 += h0.w * aw0[3]; acc1 += h0.w * aw1[3]; acc2 += h0.w * aw2[3]; acc3 += h0.w * aw3[3];
        acc0 += h1.x * aw0[4]; acc1 += h1.x * aw1[4]; acc2 += h1.x * aw2[4]; acc3 += h1.x * aw3[4];
        acc0 += h1.y * aw0[5]; acc1 += h1.y * aw1[5]; acc2 += h1.y * aw2[5]; acc3 += h1.y * aw3[5];
        acc0 += h1.z * aw0[6]; acc1 += h1.z * aw1[6]; acc2 += h1.z * aw2[6]; acc3 += h1.z * aw3[6];
        acc0 += h1.w * aw0[7]; acc1 += h1.w * aw1[7]; acc2 += h1.w * aw2[7]; acc3 += h1.w * aw3[7];
        acc0 += h2.x * aw0[8]; acc1 += h2.x * aw1[8]; acc2 += h2.x * aw2[8]; acc3 += h2.x * aw3[8];
        acc0 += h2.y * aw0[9]; acc1 += h2.y * aw1[9]; acc2 += h2.y * aw2[9]; acc3 += h2.y * aw3[9];
        float4 rv;
        rv.x = fmaxf(acc0, 0.f);
        rv.y = fmaxf(acc1, 0.f);
        rv.z = fmaxf(acc2, 0.f);
        rv.w = fmaxf(acc3, 0.f);
        *reinterpret_cast<float4*>(optr) = rv;
        optr += 4 * NS;
    }
}

extern "C" void kernel_launch(void* const* d_in, const int* in_sizes, int n_in,
                              void* d_out, int out_size, void* d_ws, size_t ws_size,
                              hipStream_t stream) {
    const float* x     = (const float*)d_in[0];
    const float* times = (const float*)d_in[1];
    const float* mask  = (const float*)d_in[2];
    const float* obsW  = (const float*)d_in[3];
    const float* attnW = (const float*)d_in[4];
    const float* recvW = (const float*)d_in[5];
    const float* recvB = (const float*)d_in[6];
    float* out = (float*)d_out;
    float* w3 = (float*)d_ws;   // 32 KiB repacked obsW (ws_size >= 32MB, R4)

    repack_obsw<<<dim3(32), dim3(256), 0, stream>>>(obsW, w3);

    // B*T = 16384 (b,t) pairs, one wave each, 8 waves per block
    raindrop_kernel<<<dim3((NB * NT) / 8), dim3(512), 0, stream>>>(
        x, times, mask, w3, attnW, recvW, recvB, out);
}

// Round 11
// 81.706 us; speedup vs baseline: 1.5545x; 1.1405x over previous
//
#include <hip/hip_runtime.h>
#include <math.h>

#define NB 32
#define NT 512
#define NS 64
#define NOBS 4
#define NEMB 32
#define NPE 16
#define NATTN 10
#define ND 26  // ATTN + PE

// obs_emb_weights LDS layout: 64 rows (sensor s) x 128 dwords (o*32+e),
// 16B-chunk XOR swizzle so per-lane ds_read_b128 of row s spreads banks.
__device__ __forceinline__ int obs_idx(int s, int chunk) {
    return (s << 7) + (((chunk ^ (s & 7)) & 31) << 2);
}

__global__ __launch_bounds__(512)
void raindrop_kernel(const float* __restrict__ x,
                     const float* __restrict__ times,
                     const float* __restrict__ mask,
                     const float* __restrict__ obsW,
                     const float* __restrict__ attnW,
                     const float* __restrict__ recvW,
                     const float* __restrict__ recvB,
                     float* __restrict__ out)
{
    // 32 KiB, reused: phase 1 = swizzled obsW tile; phase 3 = hq rows.
    // 33 KiB total -> 4 blocks/CU, 32 waves/CU (LDS is the occupancy binder).
    __shared__ float lds[NS * 128];
    __shared__ float wpe[8 * NEMB];  // 1 KiB per-wave folded-PE strips

    const int tid = threadIdx.x;

    // Stage S*OBS*EMB = 8192 floats into LDS (coalesced global float4 reads,
    // swizzled LDS writes). 512 threads x 4 iters x 4 floats.
#pragma unroll
    for (int k = 0; k < 4; ++k) {
        int i = (tid << 2) + (k << 11);
        float4 v = *reinterpret_cast<const float4*>(obsW + i);
        *reinterpret_cast<float4*>(&lds[obs_idx(i >> 7, (i & 127) >> 2)]) = v;
    }

    const int lane = tid & 63;
    const int wv = tid >> 6;
    const int bt = blockIdx.x * 8 + wv;   // one wave per (b,t)
    const int s = lane;                   // phase-1 role: lane = sensor
    const int g = lane >> 3;              // phase-3: 8 row-groups
    const int iu = lane & 7;              // phase-3: u-octet owner

    // per-lane attnW for u = iu*4+j and 32+iu*4+j (j=0..3): 80 VGPRs.
    // All indices compile-time after unroll (no scratch).
    float aw[8][NATTN];
    {
        const float2* ap0 = reinterpret_cast<const float2*>(attnW + (iu * 4) * NATTN);
        const float2* ap1 = reinterpret_cast<const float2*>(attnW + (32 + iu * 4) * NATTN);
#pragma unroll
        for (int j = 0; j < 4; ++j) {
#pragma unroll
            for (int q = 0; q < 5; ++q) {
                float2 v0 = ap0[j * 5 + q];
                aw[j][2 * q] = v0.x; aw[j][2 * q + 1] = v0.y;
                float2 v1 = ap1[j * 5 + q];
                aw[j + 4][2 * q] = v1.x; aw[j + 4][2 * q + 1] = v1.y;
            }
        }
    }

    // positional encoding (wave-uniform; div[i] = 10^(-i/2)); native sin/cos
    const float tt = times[bt];
    const float divs[8] = {1.0f, 0.31622776601683794f, 0.1f, 0.031622776601683794f,
                           0.01f, 0.0031622776601683794f, 0.001f, 0.00031622776601683794f};
    float pe[NPE];
#pragma unroll
    for (int i = 0; i < 8; ++i) {
        float ang = tt * divs[i];
        pe[2 * i]     = __sinf(ang);
        pe[2 * i + 1] = __cosf(ang);
    }

    // c0 = recvB[10:26] . pe  (uniform; recvB via s_load)
    float c0 = 0.f;
#pragma unroll
    for (int p = 0; p < NPE; ++p) c0 += recvB[NATTN + p] * pe[p];

    // w_pe: lane e (= lane&31) folds recvW[e][10..25] with pe -> LDS strip.
    float* wpw = &wpe[wv * NEMB];
    {
        const int e = lane & 31;
        const float2* rp = reinterpret_cast<const float2*>(recvW + e * ND + NATTN);
        float acc = 0.f;
#pragma unroll
        for (int p2 = 0; p2 < 8; ++p2) {
            float2 w = rp[p2];
            acc += w.x * pe[2 * p2];
            acc += w.y * pe[2 * p2 + 1];
        }
        if (lane < NEMB) wpw[e] = acc;
    }

    // per-lane inputs (coalesced: 64 lanes x 16B contiguous)
    const float4 xv = *reinterpret_cast<const float4*>(x + ((size_t)bt * NS + s) * NOBS);
    const float  mv = mask[(size_t)bt * NS + s];

    __syncthreads();  // obsW tile + wpe ready

    // hq[a] = recv_b[a] + sum_e h_e * recv_W[e][a]   (a = 0..9 only)
    // beta' = sum_e h_e * w_pe[e]
    float hq[NATTN];
#pragma unroll
    for (int a = 0; a < NATTN; ++a) hq[a] = recvB[a];  // uniform -> s_load
    float betah = 0.f;

#pragma unroll
    for (int eb = 0; eb < 8; ++eb) {  // e = eb*4 + j
        float a0 = 0.f, a1 = 0.f, a2 = 0.f, a3 = 0.f;
        {
            float4 w0 = *reinterpret_cast<const float4*>(&lds[obs_idx(s, 0 * 8 + eb)]);
            a0 += xv.x * w0.x; a1 += xv.x * w0.y; a2 += xv.x * w0.z; a3 += xv.x * w0.w;
            float4 w1 = *reinterpret_cast<const float4*>(&lds[obs_idx(s, 1 * 8 + eb)]);
            a0 += xv.y * w1.x; a1 += xv.y * w1.y; a2 += xv.y * w1.z; a3 += xv.y * w1.w;
            float4 w2 = *reinterpret_cast<const float4*>(&lds[obs_idx(s, 2 * 8 + eb)]);
            a0 += xv.z * w2.x; a1 += xv.z * w2.y; a2 += xv.z * w2.z; a3 += xv.z * w2.w;
            float4 w3 = *reinterpret_cast<const float4*>(&lds[obs_idx(s, 3 * 8 + eb)]);
            a0 += xv.w * w3.x; a1 += xv.w * w3.y; a2 += xv.w * w3.z; a3 += xv.w * w3.w;
        }
        const float h0 = fmaxf(a0, 0.f) * mv;
        const float h1 = fmaxf(a1, 0.f) * mv;
        const float h2 = fmaxf(a2, 0.f) * mv;
        const float h3 = fmaxf(a3, 0.f) * mv;

        // beta' contribution: uniform ds_read_b128 broadcast of 4 w_pe
        float4 wp = *reinterpret_cast<const float4*>(wpw + eb * 4);
        betah += h0 * wp.x + h1 * wp.y + h2 * wp.z + h3 * wp.w;

        const float* rw = recvW + (eb * 4) * ND;  // uniform base -> s_load
#pragma unroll
        for (int a = 0; a < NATTN; ++a) {
            hq[a] += h0 * rw[a] + h1 * rw[ND + a] + h2 * rw[2 * ND + a] + h3 * rw[3 * ND + a];
        }
    }

    const float beta = c0 + betah;

    __syncthreads();  // all waves done READING the obsW tile -> safe to reuse

    // Stage this wave's hq rows (wave-private region, 64 rows x 12 floats).
    float* hbase = &lds[wv * (NS * 12)];
    {
        float* hrow = hbase + s * 12;
        float4 v0 = {hq[0], hq[1], hq[2], hq[3]};
        float4 v1 = {hq[4], hq[5], hq[6], hq[7]};
        float4 v2 = {hq[8], hq[9], beta, 0.f};
        *reinterpret_cast<float4*>(hrow)     = v0;
        *reinterpret_cast<float4*>(hrow + 4) = v1;
        *reinterpret_cast<float4*>(hrow + 8) = v2;
    }
    // No barrier: this wave reads only rows its own lanes wrote, and DS ops
    // from one wave complete in program order.

    // Phase 3: 8 row-groups x 8 lanes. Per iter the SAME 3 ds_read_b128
    // serve 8 rows (48B row stride -> 8 distinct starts covering all 32
    // banks exactly once: conflict-free broadcast within 8-lane groups).
    // Lane iu computes u = iu*4+j and 32+iu*4+j; two stores/iter, each
    // 8 rows x 128B contiguous (full 64B lines).
    const float* hgbase = hbase + g * 12;
    float* optr = out + (size_t)bt * (NS * NS) + g * NS + iu * 4;
#pragma unroll 4
    for (int r = 0; r < NS; r += 8) {
        const float* hr = hgbase + r * 12;
        float4 h0 = *reinterpret_cast<const float4*>(hr);
        float4 h1 = *reinterpret_cast<const float4*>(hr + 4);
        float4 h2 = *reinterpret_cast<const float4*>(hr + 8);
        float acc[8];
#pragma unroll
        for (int j = 0; j < 8; ++j) {
            float a = h2.z;  // beta_r
            a += h0.x * aw[j][0]; a += h0.y * aw[j][1];
            a += h0.z * aw[j][2]; a += h0.w * aw[j][3];
            a += h1.x * aw[j][4]; a += h1.y * aw[j][5];
            a += h1.z * aw[j][6]; a += h1.w * aw[j][7];
            a += h2.x * aw[j][8]; a += h2.y * aw[j][9];
            acc[j] = fmaxf(a, 0.f);
        }
        float4 rv0 = {acc[0], acc[1], acc[2], acc[3]};
        float4 rv1 = {acc[4], acc[5], acc[6], acc[7]};
        *reinterpret_cast<float4*>(optr)      = rv0;  // u = iu*4 .. +3
        *reinterpret_cast<float4*>(optr + 32) = rv1;  // u = 32+iu*4 .. +3
        optr += 8 * NS;
    }
}

extern "C" void kernel_launch(void* const* d_in, const int* in_sizes, int n_in,
                              void* d_out, int out_size, void* d_ws, size_t ws_size,
                              hipStream_t stream) {
    const float* x     = (const float*)d_in[0];
    const float* times = (const float*)d_in[1];
    const float* mask  = (const float*)d_in[2];
    const float* obsW  = (const float*)d_in[3];
    const float* attnW = (const float*)d_in[4];
    const float* recvW = (const float*)d_in[5];
    const float* recvB = (const float*)d_in[6];
    float* out = (float*)d_out;

    // B*T = 16384 (b,t) pairs, one wave each, 8 waves per block
    raindrop_kernel<<<dim3((NB * NT) / 8), dim3(512), 0, stream>>>(
        x, times, mask, obsW, attnW, recvW, recvB, out);
}